// Round 1
// baseline (1309.081 us; speedup 1.0000x reference)
//
#include <hip/hip_runtime.h>

#define BB 256   // batch
#define CC 1000  // classes
#define KK 2     // mixture components per class
#define DD 128   // feature dim

// Per block: one class c. Per thread: one batch element b.
// Forward substitution L y = (z - mu), y kept fully in registers
// (all indices compile-time constants via forced full unroll).
__global__ __launch_bounds__(256, 2) void mda_head_kernel(
    const float* __restrict__ z,          // (B, D)
    const float* __restrict__ mu,         // (C, K, D)
    const float* __restrict__ logits_pi,  // (C, K)
    const float* __restrict__ covL,       // (C, K, D, D) lower-tri
    const float* __restrict__ prior,      // (C,)
    float* __restrict__ out)              // (B, C)
{
    const int c = blockIdx.x;
    const int b = threadIdx.x;
    const float* zrow = z + (size_t)b * DD;

    float lp0 = 0.f, lp1 = 0.f;

    for (int k = 0; k < KK; ++k) {          // runtime loop: keeps code size ~1x
        const size_t ck = (size_t)(c * KK + k);
        const float* Lm   = covL + ck * DD * DD;   // uniform base
        const float* mrow = mu + ck * DD;          // uniform base

        float y[DD];
        #pragma unroll
        for (int d = 0; d < DD; ++d)
            y[d] = zrow[d] - mrow[d];       // vector z load, scalar mu load

        float maha = 0.f;
        float ld   = 0.f;                   // sum of log(diag)
        float prod = 1.f;

        #pragma unroll
        for (int d = 0; d < DD; ++d) {
            const float* Lr = Lm + d * DD;  // uniform row base
            // 4 rotating accumulators -> break the dependent-FMA chain
            float a0 = 0.f, a1 = 0.f, a2 = 0.f, a3 = 0.f;
            #pragma unroll
            for (int j = 0; j < d; ++j) {
                float t = Lr[j] * y[j];     // Lr[j] wave-uniform -> s_load + SGPR operand
                if      ((j & 3) == 0) a0 += t;
                else if ((j & 3) == 1) a1 += t;
                else if ((j & 3) == 2) a2 += t;
                else                   a3 += t;
            }
            float s   = (a0 + a1) + (a2 + a3);
            float Ldd = Lr[d];
            float v   = (y[d] - s) * __builtin_amdgcn_rcpf(Ldd); // diag==1.0 -> exact
            y[d] = v;
            maha += v * v;
            prod *= Ldd;                    // grouped log for logdet
            if ((d & 31) == 31) { ld += __logf(prod); prod = 1.f; }
        }

        const float cst = 235.2482645f;     // D * log(2*pi)
        float lp = -0.5f * (maha + 2.f * ld + cst);
        lp0 = (k == 0) ? lp : lp0;
        lp1 = (k == 1) ? lp : lp1;
    }

    // fused log_softmax(logits_pi) + logsumexp over K + prior
    float lpi0 = logits_pi[c * 2 + 0];
    float lpi1 = logits_pi[c * 2 + 1];
    float mp    = fmaxf(lpi0, lpi1);
    float lsepi = mp + __logf(__expf(lpi0 - mp) + __expf(lpi1 - mp));
    float t0 = lp0 + lpi0, t1 = lp1 + lpi1;
    float mt   = fmaxf(t0, t1);
    float lset = mt + __logf(__expf(t0 - mt) + __expf(t1 - mt));
    out[(size_t)b * CC + c] = prior[c] + lset - lsepi;
}

extern "C" void kernel_launch(void* const* d_in, const int* in_sizes, int n_in,
                              void* d_out, int out_size, void* d_ws, size_t ws_size,
                              hipStream_t stream) {
    const float* z         = (const float*)d_in[0];
    const float* mu        = (const float*)d_in[1];
    const float* logits_pi = (const float*)d_in[2];
    const float* covL      = (const float*)d_in[3];
    const float* prior     = (const float*)d_in[4];
    float* out = (float*)d_out;

    dim3 grid(CC), block(BB);
    hipLaunchKernelGGL(mda_head_kernel, grid, block, 0, stream,
                       z, mu, logits_pi, covL, prior, out);
}

// Round 2
// 203.295 us; speedup vs baseline: 6.4393x; 6.4393x over previous
//
#include <hip/hip_runtime.h>
#include <cstdint>

#define CC 1000
#define KK 2
#define DD 128
#define BB 256
#define NSWEEP 4

typedef short bf16x8 __attribute__((ext_vector_type(8)));
typedef float f32x16 __attribute__((ext_vector_type(16)));

__device__ __forceinline__ uint32_t f2bf(float f) {
    uint32_t x = __builtin_bit_cast(uint32_t, f);
    uint32_t r = x + 0x7FFFu + ((x >> 16) & 1u);
    return r >> 16;
}
__device__ __forceinline__ float bflo(uint32_t u) { return __builtin_bit_cast(float, u << 16); }
__device__ __forceinline__ float bfhi(uint32_t u) { return __builtin_bit_cast(float, u & 0xFFFF0000u); }

// XOR swizzle: relocate 16B units within a 256B row to spread banks.
__device__ __forceinline__ int swz(int row, int byteInRow) {
    return row * 256 + (byteInRow ^ ((row & 15) << 4));
}

__global__ __launch_bounds__(256, 1) void mda_kernel(
    const float* __restrict__ z,          // (B, D)
    const float* __restrict__ mu,         // (C, K, D)
    const float* __restrict__ logits_pi,  // (C, K)
    const float* __restrict__ covL,       // (C, K, D, D)
    const float* __restrict__ prior,      // (C,)
    float* __restrict__ out)              // (B, C)
{
    __shared__ char Eb[DD * DD * 2];   // 32 KB bf16: -strict_lower(L)/diag, band zero-filled
    __shared__ char Rb[BB * DD * 2];   // 64 KB bf16: R[b][d] = (z-mu)*rdiag
    __shared__ char Yb[BB * DD * 2];   // 64 KB bf16: Y[b][d]; also P0 scratch (rdiag + logdet)

    const int c   = blockIdx.x;
    const int tid = threadIdx.x;
    const int w   = tid >> 6;
    const int l   = tid & 63;
    const int l31 = l & 31;
    const int hp  = l >> 5;            // lane half
    const int bbase = w * 64;          // wave's column slab
    const int b0 = bbase + l31;        // t=0 column
    const int b1 = bbase + 32 + l31;   // t=1 column

    float lp00 = 0.f, lp01 = 0.f, lp10 = 0.f, lp11 = 0.f;

    for (int k = 0; k < KK; ++k) {
        __syncthreads();  // protect E/R/Y reuse across k iterations

        const int64_t ck = (int64_t)(c * KK + k);
        const float* Lm  = covL + ck * DD * DD;
        const float* muv = mu + ck * DD;

        // ---- P0: diag -> rdiag (Yb[0..512)) + logdet partials (Yb[512..520)) ----
        if (tid < DD) {
            float dg = Lm[tid * DD + tid];
            float rd = 1.0f / dg;
            *(float*)(Yb + tid * 4) = rd;
            float lg = __logf(dg);
            #pragma unroll
            for (int off = 32; off; off >>= 1) lg += __shfl_down(lg, off, 64);
            if (l == 0) *(float*)(Yb + 512 + w * 4) = lg;
        }
        __syncthreads();
        const float sld = *(float*)(Yb + 512) + *(float*)(Yb + 516);  // sum log diag

        // ---- P1a: stage E = -strict_lower(L)*rdiag[row], bf16, swizzled ----
        #pragma unroll
        for (int q = 0; q < 16; ++q) {
            int flat = (tid + 256 * q) * 4;
            int row = flat >> 7, j0 = flat & 127;
            if (j0 <= (row | 31)) {              // only the read band needs zero-fill
                float4 v = make_float4(0.f, 0.f, 0.f, 0.f);
                if (j0 < row) v = *(const float4*)(Lm + row * DD + j0);
                float rd = *(const float*)(Yb + row * 4);
                float e0 = (j0 + 0 < row) ? -v.x * rd : 0.f;
                float e1 = (j0 + 1 < row) ? -v.y * rd : 0.f;
                float e2 = (j0 + 2 < row) ? -v.z * rd : 0.f;
                float e3 = (j0 + 3 < row) ? -v.w * rd : 0.f;
                uint2 p;
                p.x = f2bf(e0) | (f2bf(e1) << 16);
                p.y = f2bf(e2) | (f2bf(e3) << 16);
                *(uint2*)(Eb + swz(row, j0 * 2)) = p;
            }
        }

        // ---- P1b: stage R[b][d] = (z[b][d] - mu[d]) * rdiag[d], bf16, swizzled ----
        #pragma unroll
        for (int q = 0; q < 32; ++q) {
            int flat = (tid + 256 * q) * 4;
            int b = flat >> 7, d0 = flat & 127;
            float4 zv = *(const float4*)(z + b * DD + d0);
            float4 mv = *(const float4*)(muv + d0);
            float4 rv = *(const float4*)(Yb + d0 * 4);   // rdiag[d0..d0+3]
            float r0 = (zv.x - mv.x) * rv.x;
            float r1 = (zv.y - mv.y) * rv.y;
            float r2 = (zv.z - mv.z) * rv.z;
            float r3 = (zv.w - mv.w) * rv.w;
            uint2 p;
            p.x = f2bf(r0) | (f2bf(r1) << 16);
            p.y = f2bf(r2) | (f2bf(r3) << 16);
            *(uint2*)(Rb + swz(b, d0 * 2)) = p;
        }
        __syncthreads();

        // ---- P2: block Gauss-Seidel sweeps  Y <- R + E*Y  (E holds -Etilde) ----
        // Wave-private column slab => no barriers needed inside.
        float macc0 = 0.f, macc1 = 0.f;

        for (int it = 0; it < NSWEEP; ++it) {
            for (int i = 0; i < 4; ++i) {        // m-tile: output rows [32i, 32i+32)
                f32x16 acc0, acc1;
                // acc init = R tile (C-layout: col=lane&31, row=(p&3)+8(p>>2)+4(lane>>5))
                #pragma unroll
                for (int P = 0; P < 4; ++P) {
                    int d0 = 32 * i + 8 * P + 4 * hp;
                    uint2 ua = *(const uint2*)(Rb + swz(b0, d0 * 2));
                    uint2 ub = *(const uint2*)(Rb + swz(b1, d0 * 2));
                    acc0[4*P+0] = bflo(ua.x); acc0[4*P+1] = bfhi(ua.x);
                    acc0[4*P+2] = bflo(ua.y); acc0[4*P+3] = bfhi(ua.y);
                    acc1[4*P+0] = bflo(ub.x); acc1[4*P+1] = bfhi(ub.x);
                    acc1[4*P+2] = bflo(ub.y); acc1[4*P+3] = bfhi(ub.y);
                }
                // K loop: k < 32(i+1)  (triangular trim)
                for (int s = 0; s < 2 * (i + 1); ++s) {
                    int kko = (16 * s + 8 * hp) * 2;   // byte offset of k-run in row
                    bf16x8 A = *(const bf16x8*)(Eb + swz(32 * i + l31, kko));
                    const char* Bsrc = (it == 0 && s >= 2 * i) ? Rb : Yb;
                    bf16x8 B0 = *(const bf16x8*)(Bsrc + swz(b0, kko));
                    bf16x8 B1 = *(const bf16x8*)(Bsrc + swz(b1, kko));
                    acc0 = __builtin_amdgcn_mfma_f32_32x32x16_bf16(A, B0, acc0, 0, 0, 0);
                    acc1 = __builtin_amdgcn_mfma_f32_32x32x16_bf16(A, B1, acc1, 0, 0, 0);
                }
                if (it < NSWEEP - 1) {
                    // write Y tile back (bf16, packed pairs of adjacent rows)
                    #pragma unroll
                    for (int P = 0; P < 4; ++P) {
                        int d0 = 32 * i + 8 * P + 4 * hp;
                        uint2 ua, ub;
                        ua.x = f2bf(acc0[4*P+0]) | (f2bf(acc0[4*P+1]) << 16);
                        ua.y = f2bf(acc0[4*P+2]) | (f2bf(acc0[4*P+3]) << 16);
                        ub.x = f2bf(acc1[4*P+0]) | (f2bf(acc1[4*P+1]) << 16);
                        ub.y = f2bf(acc1[4*P+2]) | (f2bf(acc1[4*P+3]) << 16);
                        *(uint2*)(Yb + swz(b0, d0 * 2)) = ua;
                        *(uint2*)(Yb + swz(b1, d0 * 2)) = ub;
                    }
                } else {
                    // final sweep: square-accumulate fp32 acc directly
                    #pragma unroll
                    for (int p = 0; p < 16; ++p) {
                        macc0 += acc0[p] * acc0[p];
                        macc1 += acc1[p] * acc1[p];
                    }
                }
            }
        }

        // combine the two lane-halves (each holds 16 of 32 rows per tile)
        macc0 += __shfl_xor(macc0, 32, 64);
        macc1 += __shfl_xor(macc1, 32, 64);

        const float CST = 235.2482646f;  // 128 * log(2*pi)
        float l0 = -0.5f * (macc0 + 2.f * sld + CST);
        float l1 = -0.5f * (macc1 + 2.f * sld + CST);
        if (k == 0) { lp00 = l0; lp01 = l1; }
        else        { lp10 = l0; lp11 = l1; }
    }

    // ---- epilogue: prior + LSE_k(lp + logpi) - LSE_k(logpi) ----
    if (l < 32) {
        float pi0 = logits_pi[c * 2 + 0];
        float pi1 = logits_pi[c * 2 + 1];
        float mp = fmaxf(pi0, pi1);
        float lsepi = mp + __logf(__expf(pi0 - mp) + __expf(pi1 - mp));
        float pr = prior[c];
        {   // t = 0 columns
            float t0 = lp00 + pi0, t1 = lp10 + pi1;
            float mt = fmaxf(t0, t1);
            float v = pr + mt + __logf(__expf(t0 - mt) + __expf(t1 - mt)) - lsepi;
            out[(size_t)b0 * CC + c] = v;
        }
        {   // t = 1 columns
            float t0 = lp01 + pi0, t1 = lp11 + pi1;
            float mt = fmaxf(t0, t1);
            float v = pr + mt + __logf(__expf(t0 - mt) + __expf(t1 - mt)) - lsepi;
            out[(size_t)b1 * CC + c] = v;
        }
    }
}

extern "C" void kernel_launch(void* const* d_in, const int* in_sizes, int n_in,
                              void* d_out, int out_size, void* d_ws, size_t ws_size,
                              hipStream_t stream) {
    const float* z         = (const float*)d_in[0];
    const float* mu        = (const float*)d_in[1];
    const float* logits_pi = (const float*)d_in[2];
    const float* covL      = (const float*)d_in[3];
    const float* prior     = (const float*)d_in[4];
    float* out = (float*)d_out;

    hipLaunchKernelGGL(mda_kernel, dim3(CC), dim3(BB), 0, stream,
                       z, mu, logits_pi, covL, prior, out);
}

// Round 3
// 195.971 us; speedup vs baseline: 6.6800x; 1.0374x over previous
//
#include <hip/hip_runtime.h>
#include <cstdint>

#define CC 1000
#define KK 2
#define DD 128
#define HB 128     // batch rows per block (B=256 split across 2 blocks)
#define TLOC 2     // local diag-block iterations (error ~ ||E||^3 ~ 1e-3)

typedef short bf16x8 __attribute__((ext_vector_type(8)));
typedef float f32x16 __attribute__((ext_vector_type(16)));

__device__ __forceinline__ uint32_t f2bf(float f) {
    uint32_t x = __builtin_bit_cast(uint32_t, f);
    return (x + 0x7FFFu + ((x >> 16) & 1u)) >> 16;
}
__device__ __forceinline__ float bflo(uint32_t u){ return __builtin_bit_cast(float, u << 16); }
__device__ __forceinline__ float bfhi(uint32_t u){ return __builtin_bit_cast(float, u & 0xFFFF0000u); }
// XOR-swizzle 16B units within a 256B row
__device__ __forceinline__ int swz(int row, int b){ return row*256 + (b ^ ((row & 15) << 4)); }

__global__ __launch_bounds__(256, 3) void mda_kernel(
    const float* __restrict__ z,          // (B, D)
    const float* __restrict__ mu,         // (C, K, D)
    const float* __restrict__ logits_pi,  // (C, K)
    const float* __restrict__ covL,       // (C, K, D, D)
    const float* __restrict__ prior,      // (C,)
    float* __restrict__ out)              // (B, C)
{
    __shared__ __align__(16) char RY[HB * 256];  // 32 KB bf16, r then y in place
    __shared__ float RD[DD];                     // 1/diag
    __shared__ float LG[2];                      // logdet partials

    const int bid = blockIdx.x;
    const int c   = bid % CC;
    const int h   = bid / CC;          // batch half
    const int tid = threadIdx.x;
    const int w   = tid >> 6, l = tid & 63, l31 = l & 31, hp = l >> 5;
    const int brow = w * 32 + l31;     // this lane's private LDS row (batch col)

    float lp0 = 0.f, lp1 = 0.f;

    for (int k = 0; k < KK; ++k) {
        __syncthreads();               // protect RY/RD/LG reuse across k
        const float* Lm  = covL + (int64_t)(c*KK + k) * (DD*DD);
        const float* muv = mu + (size_t)(c*KK + k) * DD;

        // P0: rdiag + logdet
        if (tid < DD) {
            float dg = Lm[(size_t)tid * DD + tid];
            RD[tid] = 1.0f / dg;
            float lg = __logf(dg);
            #pragma unroll
            for (int o = 32; o; o >>= 1) lg += __shfl_down(lg, o, 64);
            if (l == 0) LG[tid >> 6] = lg;
        }

        // P1: R[row][d] = z - mu  (unscaled), bf16, swizzled
        #pragma unroll
        for (int q = 0; q < 16; ++q) {
            int flat = (tid + 256*q) * 4;
            int row = flat >> 7, d0 = flat & 127;
            float4 zv = *(const float4*)(z + (size_t)(h*HB + row)*DD + d0);
            float4 mv = *(const float4*)(muv + d0);
            uint2 u;
            u.x = f2bf(zv.x - mv.x) | (f2bf(zv.y - mv.y) << 16);
            u.y = f2bf(zv.z - mv.z) | (f2bf(zv.w - mv.w) << 16);
            *(uint2*)(RY + swz(row, d0*2)) = u;
        }
        __syncthreads();
        const float sld = LG[0] + LG[1];

        // P2: blocked forward substitution, wave-private rows, no barriers
        float macc = 0.f;
        #pragma unroll
        for (int i = 0; i < 4; ++i) {
            const float* rowL = Lm + (size_t)(32*i + l31) * DD;

            // acc_off = r_i  (C-layout: col=lane&31, row=(p&3)+8(p>>2)+4hp)
            f32x16 acc_off;
            #pragma unroll
            for (int P = 0; P < 4; ++P) {
                int d0 = 32*i + 8*P + 4*hp;
                uint2 u = *(const uint2*)(RY + swz(brow, d0*2));
                acc_off[4*P+0] = bflo(u.x); acc_off[4*P+1] = bfhi(u.x);
                acc_off[4*P+2] = bflo(u.y); acc_off[4*P+3] = bfhi(u.y);
            }

            // diag-block A-frags (masked j<row), issued early; reused TLOC times
            bf16x8 Ad[2];
            #pragma unroll
            for (int s2 = 0; s2 < 2; ++s2) {
                int jb = 16*s2 + 8*hp;  // within-tile col base
                const float4* ap = (const float4*)(rowL + 32*i + jb);
                float4 a = ap[0], b = ap[1];
                bf16x8 A;
                A[0] = (short)(jb+0 < l31 ? f2bf(-a.x) : 0);
                A[1] = (short)(jb+1 < l31 ? f2bf(-a.y) : 0);
                A[2] = (short)(jb+2 < l31 ? f2bf(-a.z) : 0);
                A[3] = (short)(jb+3 < l31 ? f2bf(-a.w) : 0);
                A[4] = (short)(jb+4 < l31 ? f2bf(-b.x) : 0);
                A[5] = (short)(jb+5 < l31 ? f2bf(-b.y) : 0);
                A[6] = (short)(jb+6 < l31 ? f2bf(-b.z) : 0);
                A[7] = (short)(jb+7 < l31 ? f2bf(-b.w) : 0);
                Ad[s2] = A;
            }

            float rdv[16];
            #pragma unroll
            for (int p = 0; p < 16; ++p)
                rdv[p] = RD[32*i + (p&3) + 8*(p>>2) + 4*hp];

            // off-diagonal: acc_off -= L_ij * y_j  (exact, y_j final)
            #pragma unroll
            for (int j = 0; j < i; ++j) {
                #pragma unroll
                for (int s2 = 0; s2 < 2; ++s2) {
                    int jb = 32*j + 16*s2 + 8*hp;
                    const float4* ap = (const float4*)(rowL + jb);
                    float4 a = ap[0], b = ap[1];
                    bf16x8 A;
                    A[0]=(short)f2bf(-a.x); A[1]=(short)f2bf(-a.y);
                    A[2]=(short)f2bf(-a.z); A[3]=(short)f2bf(-a.w);
                    A[4]=(short)f2bf(-b.x); A[5]=(short)f2bf(-b.y);
                    A[6]=(short)f2bf(-b.z); A[7]=(short)f2bf(-b.w);
                    bf16x8 B = *(const bf16x8*)(RY + swz(brow, jb*2));
                    acc_off = __builtin_amdgcn_mfma_f32_32x32x16_bf16(A, B, acc_off, 0,0,0);
                }
            }

            // local diag iterations: y^{t+1} = rd .* (acc_off - S_ii y^t)
            float yv[16];
            #pragma unroll
            for (int p = 0; p < 16; ++p) yv[p] = rdv[p] * acc_off[p];  // y^0
            #pragma unroll
            for (int P = 0; P < 4; ++P) {   // write y^0
                int d0 = 32*i + 8*P + 4*hp;
                uint2 u;
                u.x = f2bf(yv[4*P+0]) | (f2bf(yv[4*P+1]) << 16);
                u.y = f2bf(yv[4*P+2]) | (f2bf(yv[4*P+3]) << 16);
                *(uint2*)(RY + swz(brow, d0*2)) = u;
            }
            #pragma unroll
            for (int t = 1; t <= TLOC; ++t) {
                f32x16 acc = acc_off;
                bf16x8 B0 = *(const bf16x8*)(RY + swz(brow, (32*i + 8*hp)*2));
                bf16x8 B1 = *(const bf16x8*)(RY + swz(brow, (32*i + 16 + 8*hp)*2));
                acc = __builtin_amdgcn_mfma_f32_32x32x16_bf16(Ad[0], B0, acc, 0,0,0);
                acc = __builtin_amdgcn_mfma_f32_32x32x16_bf16(Ad[1], B1, acc, 0,0,0);
                #pragma unroll
                for (int p = 0; p < 16; ++p) yv[p] = rdv[p] * acc[p];
                if (t < TLOC || i < 3) {    // last tile's final y never re-read
                    #pragma unroll
                    for (int P = 0; P < 4; ++P) {
                        int d0 = 32*i + 8*P + 4*hp;
                        uint2 u;
                        u.x = f2bf(yv[4*P+0]) | (f2bf(yv[4*P+1]) << 16);
                        u.y = f2bf(yv[4*P+2]) | (f2bf(yv[4*P+3]) << 16);
                        *(uint2*)(RY + swz(brow, d0*2)) = u;
                    }
                }
            }
            #pragma unroll
            for (int p = 0; p < 16; ++p) macc += yv[p] * yv[p];  // fp32 final y
        }

        macc += __shfl_xor(macc, 32, 64);   // combine row-halves
        const float CST = 235.2482645f;     // 128*log(2*pi)
        float lp = -0.5f * (macc + 2.f * sld + CST);
        if (k == 0) lp0 = lp; else lp1 = lp;
    }

    // epilogue: prior + LSE_k(lp + logpi) - LSE_k(logpi)
    if (hp == 0) {
        float pi0 = logits_pi[c*2+0], pi1 = logits_pi[c*2+1];
        float mp = fmaxf(pi0, pi1);
        float lsepi = mp + __logf(__expf(pi0-mp) + __expf(pi1-mp));
        float t0 = lp0 + pi0, t1 = lp1 + pi1;
        float mt = fmaxf(t0, t1);
        float v = prior[c] + mt + __logf(__expf(t0-mt) + __expf(t1-mt)) - lsepi;
        out[(size_t)(h*HB + brow)*CC + c] = v;
    }
}

extern "C" void kernel_launch(void* const* d_in, const int* in_sizes, int n_in,
                              void* d_out, int out_size, void* d_ws, size_t ws_size,
                              hipStream_t stream) {
    const float* z         = (const float*)d_in[0];
    const float* mu        = (const float*)d_in[1];
    const float* logits_pi = (const float*)d_in[2];
    const float* covL      = (const float*)d_in[3];
    const float* prior     = (const float*)d_in[4];
    float* out = (float*)d_out;

    hipLaunchKernelGGL(mda_kernel, dim3(2*CC), dim3(256), 0, stream,
                       z, mu, logits_pi, covL, prior, out);
}

// Round 4
// 112.303 us; speedup vs baseline: 11.6567x; 1.7450x over previous
//
#include <hip/hip_runtime.h>
#include <cstdint>

#define CC 1000
#define KK 2
#define DD 128

typedef short bf16x8 __attribute__((ext_vector_type(8)));
typedef float f32x16 __attribute__((ext_vector_type(16)));
typedef int   i32x4  __attribute__((ext_vector_type(4)));

__device__ __forceinline__ uint32_t f2bf(float f) {
    uint32_t x = __builtin_bit_cast(uint32_t, f);
    return (x + 0x7FFFu + ((x >> 16) & 1u)) >> 16;
}
__device__ __forceinline__ uint32_t pk2(float lo, float hi) {
    return f2bf(lo) | (f2bf(hi) << 16);
}
__device__ __forceinline__ f32x16 zero16() {
    f32x16 v;
    #pragma unroll
    for (int p = 0; p < 16; ++p) v[p] = 0.f;
    return v;
}
__device__ __forceinline__ bf16x8 mk_frag(const uint32_t* wv) {
    i32x4 t;
    t[0] = (int)wv[0]; t[1] = (int)wv[1]; t[2] = (int)wv[2]; t[3] = (int)wv[3];
    return __builtin_bit_cast(bf16x8, t);
}

// C-layout fp32 tile -> 8 packed-bf16 B-fragment words (s=0: out[0..3], s=1: out[4..7]).
// Lane (col n=l31, half hp) holds rows (p&3)+8*(p>>2)+4*hp. B-frag word j for step s
// needs rows {16s+8hp+2j, +1}; half of those live in the partner lane (l^32).
__device__ __forceinline__ void build_frags(const f32x16& t, uint32_t* out, int hp) {
    uint32_t W[8];
    #pragma unroll
    for (int q = 0; q < 8; ++q) W[q] = pk2(t[2*q], t[2*q+1]);
    // rows: W0={4hp,+1} W1={4hp+2,+3} W2={8+4hp,+1} W3={8+4hp+2,+3} W4..W7 = +16
    uint32_t s0 = (uint32_t)__shfl_xor((int)W[0], 32, 64);
    uint32_t s1 = (uint32_t)__shfl_xor((int)W[1], 32, 64);
    uint32_t s2 = (uint32_t)__shfl_xor((int)W[2], 32, 64);
    uint32_t s3 = (uint32_t)__shfl_xor((int)W[3], 32, 64);
    uint32_t s4 = (uint32_t)__shfl_xor((int)W[4], 32, 64);
    uint32_t s5 = (uint32_t)__shfl_xor((int)W[5], 32, 64);
    uint32_t s6 = (uint32_t)__shfl_xor((int)W[6], 32, 64);
    uint32_t s7 = (uint32_t)__shfl_xor((int)W[7], 32, 64);
    out[0] = hp ? s2   : W[0];
    out[1] = hp ? s3   : W[1];
    out[2] = hp ? W[2] : s0;
    out[3] = hp ? W[3] : s1;
    out[4] = hp ? s6   : W[4];
    out[5] = hp ? s7   : W[5];
    out[6] = hp ? W[6] : s4;
    out[7] = hp ? W[7] : s5;
}

// LDS layout (bytes, 16B-aligned, rows stride 80B = bank-spread):
//   [0,15360)      Eoff: 6 off-diag blocks, A-layout, holds -L_ij
//   [15360,25600)  Sm:   4 diag blocks, first -S_i, overwritten by M'_i
//   [25600,35840)  Tt:   4 diag blocks, (I - S_i) transposed (B-layout)
__global__ __launch_bounds__(512, 4) void mda_kernel(
    const float* __restrict__ z,          // (B, D)
    const float* __restrict__ mu,         // (C, K, D)
    const float* __restrict__ logits_pi,  // (C, K)
    const float* __restrict__ covL,       // (C, K, D, D)
    const float* __restrict__ prior,      // (C,)
    float* __restrict__ out)              // (B, C)
{
    __shared__ __align__(16) char E[35840];
    __shared__ float RD[DD];
    __shared__ float LG[2];

    const int c   = blockIdx.x;
    const int tid = threadIdx.x;
    const int w   = tid >> 6, l = tid & 63, l31 = l & 31, hp = l >> 5;
    const int bcol = w * 32 + l31;              // this lane's batch column
    const float* zb = z + (size_t)bcol * DD;

    float lp0 = 0.f, lp1 = 0.f;

    for (int k = 0; k < KK; ++k) {
        const float* Lm  = covL + (int64_t)(c*KK + k) * (DD*DD);
        const float* muv = mu + (size_t)(c*KK + k) * DD;

        // ---- phase A: rdiag + logdet (waves 0,1). Safe vs. prev solve: solve reads no RD/LG.
        if (tid < DD) {
            float dg = Lm[(size_t)tid * DD + tid];
            RD[tid] = 1.0f / dg;
            float lg = __logf(dg);
            #pragma unroll
            for (int o = 32; o; o >>= 1) lg += __shfl_down(lg, o, 64);
            if (l == 0) LG[tid >> 6] = lg;
        }
        __syncthreads();
        const float sld = LG[0] + LG[1];        // into register before LG is reused

        // ---- phase B: stage E (coalesced float4 row loads, one conversion total)
        {
            const int bi[6] = {1,2,2,3,3,3}, bj[6] = {0,0,1,0,1,2};
            #pragma unroll
            for (int rep = 0; rep < 3; ++rep) {  // 6 blocks * 32 rows * 8 float4 = 1536 tasks
                int t2 = tid + 512*rep;
                int blk = t2 >> 8, r = (t2 >> 3) & 31, c4 = t2 & 7;
                float4 v = *(const float4*)(Lm + (size_t)(32*bi[blk] + r)*DD + 32*bj[blk] + 4*c4);
                uint2 u; u.x = pk2(-v.x, -v.y); u.y = pk2(-v.z, -v.w);
                *(uint2*)(E + blk*2560 + r*80 + 8*c4) = u;
            }
            #pragma unroll
            for (int rep = 0; rep < 2; ++rep) {  // 4 diag blocks * 32 * 8 = 1024 tasks
                int t3 = tid + 512*rep;
                int ib = t3 >> 8, r = (t3 >> 3) & 31, c4 = t3 & 7;
                float4 v = *(const float4*)(Lm + (size_t)(32*ib + r)*DD + 32*ib + 4*c4);
                float rdr = RD[32*ib + r];
                float vv[4] = {v.x, v.y, v.z, v.w};
                float sm[4];
                #pragma unroll
                for (int e = 0; e < 4; ++e) {
                    int n = 4*c4 + e;
                    float se = (n < r) ? -vv[e]*rdr : 0.f;
                    sm[e] = se;
                    float tv = (n == r) ? 1.f : se;      // (I - S)[r][n]
                    *(unsigned short*)(E + 25600 + ib*2560 + n*80 + 2*r) = (unsigned short)f2bf(tv);
                }
                uint2 u; u.x = pk2(sm[0], sm[1]); u.y = pk2(sm[2], sm[3]);
                *(uint2*)(E + 15360 + ib*2560 + r*80 + 8*c4) = u;
            }
        }
        __syncthreads();

        // ---- M' compute: wave w<4 owns tile w.  M' = (I + (-S)(I-S)) * D^-1
        if (w < 4) {
            const char* SmB = E + 15360 + w*2560;
            const char* TtB = E + 25600 + w*2560;
            bf16x8 A0 = *(const bf16x8*)(SmB + l31*80 + 16*hp);
            bf16x8 A1 = *(const bf16x8*)(SmB + l31*80 + 32 + 16*hp);
            bf16x8 B0 = *(const bf16x8*)(TtB + l31*80 + 16*hp);
            bf16x8 B1 = *(const bf16x8*)(TtB + l31*80 + 32 + 16*hp);
            f32x16 mm = zero16();
            mm = __builtin_amdgcn_mfma_f32_32x32x16_bf16(A0, B0, mm, 0,0,0);
            mm = __builtin_amdgcn_mfma_f32_32x32x16_bf16(A1, B1, mm, 0,0,0);
            float rdn = RD[32*w + l31];          // column scale (n = l31)
            char* SmW = E + 15360 + w*2560;
            #pragma unroll
            for (int p = 0; p < 16; ++p) {
                int rowp = (p&3) + 8*(p>>2) + 4*hp;
                float mval = (mm[p] + ((rowp == l31) ? 1.f : 0.f)) * rdn;
                *(unsigned short*)(SmW + rowp*80 + 2*l31) = (unsigned short)f2bf(mval);
            }
        }
        __syncthreads();

        // ---- solve: per wave, 32 batch cols, everything in registers
        uint32_t yW[3][8];
        float macc = 0.f;
        #pragma unroll
        for (int i = 0; i < 4; ++i) {
            f32x16 acc;
            #pragma unroll
            for (int q = 0; q < 4; ++q) {        // r_i fp32 straight from z/mu (C-layout)
                float4 zv = *(const float4*)(zb + 32*i + 8*q + 4*hp);
                float4 mv = *(const float4*)(muv + 32*i + 8*q + 4*hp);
                acc[4*q+0] = zv.x - mv.x;
                acc[4*q+1] = zv.y - mv.y;
                acc[4*q+2] = zv.z - mv.z;
                acc[4*q+3] = zv.w - mv.w;
            }
            #pragma unroll
            for (int j = 0; j < i; ++j) {        // t_i = r_i - sum_j L_ij y_j
                const char* Ep = E + (i*(i-1)/2 + j)*2560 + l31*80 + 16*hp;
                bf16x8 A0 = *(const bf16x8*)(Ep);
                bf16x8 A1 = *(const bf16x8*)(Ep + 32);
                acc = __builtin_amdgcn_mfma_f32_32x32x16_bf16(A0, mk_frag(&yW[j][0]), acc, 0,0,0);
                acc = __builtin_amdgcn_mfma_f32_32x32x16_bf16(A1, mk_frag(&yW[j][4]), acc, 0,0,0);
            }
            uint32_t tF[8];
            build_frags(acc, tF, hp);            // t -> bf16 B-frags, no LDS
            const char* Mp = E + 15360 + i*2560 + l31*80 + 16*hp;
            bf16x8 MA0 = *(const bf16x8*)(Mp);
            bf16x8 MA1 = *(const bf16x8*)(Mp + 32);
            f32x16 yv = zero16();                // y_i = M'_i t_i
            yv = __builtin_amdgcn_mfma_f32_32x32x16_bf16(MA0, mk_frag(&tF[0]), yv, 0,0,0);
            yv = __builtin_amdgcn_mfma_f32_32x32x16_bf16(MA1, mk_frag(&tF[4]), yv, 0,0,0);
            #pragma unroll
            for (int p = 0; p < 16; ++p) macc += yv[p] * yv[p];
            if (i < 3) build_frags(yv, yW[i], hp);
        }
        macc += __shfl_xor(macc, 32, 64);        // combine row-halves per column

        const float CST = 235.2482645f;          // 128*log(2*pi)
        float lp = -0.5f * (macc + 2.f * sld + CST);
        if (k == 0) lp0 = lp; else lp1 = lp;
    }

    // ---- epilogue: prior + LSE_k(lp + logpi) - LSE_k(logpi)
    if (hp == 0) {
        float pi0 = logits_pi[c*2+0], pi1 = logits_pi[c*2+1];
        float mp = fmaxf(pi0, pi1);
        float lsepi = mp + __logf(__expf(pi0-mp) + __expf(pi1-mp));
        float t0 = lp0 + pi0, t1 = lp1 + pi1;
        float mt = fmaxf(t0, t1);
        float v = prior[c] + mt + __logf(__expf(t0-mt) + __expf(t1-mt)) - lsepi;
        out[(size_t)bcol * CC + c] = v;
    }
}

extern "C" void kernel_launch(void* const* d_in, const int* in_sizes, int n_in,
                              void* d_out, int out_size, void* d_ws, size_t ws_size,
                              hipStream_t stream) {
    const float* z         = (const float*)d_in[0];
    const float* mu        = (const float*)d_in[1];
    const float* logits_pi = (const float*)d_in[2];
    const float* covL      = (const float*)d_in[3];
    const float* prior     = (const float*)d_in[4];
    float* out = (float*)d_out;

    hipLaunchKernelGGL(mda_kernel, dim3(CC), dim3(512), 0, stream,
                       z, mu, logits_pi, covL, prior, out);
}